// Round 5
// baseline (82.810 us; speedup 1.0000x reference)
//
#include <hip/hip_runtime.h>

#define NV 50000
#define NJ 24
#define NBETA 10
#define NP 207          // (24-1)*9
#define NROWS 150000    // NV*3

// K1 grid
#define K1_BLOCKS 196   // 196 * 256 = 50176 >= 50000

// K3a: 64 rows / block, LDS-staged tile
#define K3A_BLOCKS 2344 // ceil(150000/64); last block has 48 rows

// ws layout (float offsets)
#define PARTIAL_OFF 0        // 196*72 = 14112 floats
#define LROT_OFF    14592    // 208 floats (207 + zero pad); byte 58368, 16B-aligned
#define M_OFF       14848    // 24*12 = 288 floats

__device__ const int d_par[NJ] = {0,0,0,0,1,2,3,4,5,6,7,8,9,9,9,12,13,14,16,17,18,19,20,21};
__device__ const int d_lvl[NJ] = {0,1,1,1,2,2,2,3,3,3,4,4,4,4,4,5,5,5,6,6,7,7,8,8};

// ---------------------------------------------------------------------------
// K1: per-block partial J = J_regressor @ v_shaped  (one 256-vertex tile/block)
// ---------------------------------------------------------------------------
__global__ __launch_bounds__(256) void k1_partialJ(
    const float* __restrict__ betas, const float* __restrict__ shapedirs,
    const float* __restrict__ v_template, const float* __restrict__ Jreg,
    float* __restrict__ ws)
{
    __shared__ float sd[256 * 30];
    __shared__ float vt[256 * 3];
    __shared__ float bet[NBETA];
    __shared__ float red[4 * 72];

    const int t = threadIdx.x;
    const int blk = blockIdx.x;
    if (t < NBETA) bet[t] = betas[t];

    const int vbase = blk * 256;
    const int nv    = min(256, NV - vbase);   // 256, or 80 for last block
    {
        const int nf4 = (nv * 30) >> 2;       // divisible by 4 for nv in {256,80}
        const float4* sdg = (const float4*)(shapedirs + (size_t)vbase * 30);
        for (int i = t; i < nf4; i += 256) ((float4*)sd)[i] = sdg[i];
        const float* vtg = v_template + (size_t)vbase * 3;
        const int nf3 = nv * 3;
        for (int i = t; i < nf3; i += 256) vt[i] = vtg[i];
    }
    __syncthreads();

    float accJ[72];
#pragma unroll
    for (int q = 0; q < 72; q++) accJ[q] = 0.f;

    const int v = vbase + t;
    if (v < NV) {
        float vs0 = vt[t * 3 + 0], vs1 = vt[t * 3 + 1], vs2 = vt[t * 3 + 2];
#pragma unroll
        for (int i = 0; i < NBETA; i++) {
            const float b = bet[i];
            vs0 += sd[t * 30 + 0 * 10 + i] * b;
            vs1 += sd[t * 30 + 1 * 10 + i] * b;
            vs2 += sd[t * 30 + 2 * 10 + i] * b;
        }
#pragma unroll
        for (int j = 0; j < NJ; j++) {
            const float w = Jreg[(size_t)j * NV + v];
            accJ[j * 3 + 0] += w * vs0;
            accJ[j * 3 + 1] += w * vs1;
            accJ[j * 3 + 2] += w * vs2;
        }
    }

    const int lane = t & 63, wv = t >> 6;
#pragma unroll
    for (int q = 0; q < 72; q++) {
        float x = accJ[q];
#pragma unroll
        for (int m = 1; m < 64; m <<= 1) x += __shfl_xor(x, m);
        if (lane == 0) red[wv * 72 + q] = x;
    }
    __syncthreads();
    if (t < 72)
        ws[PARTIAL_OFF + blk * 72 + t] = red[t] + red[72 + t] + red[144 + t] + red[216 + t];
}

// ---------------------------------------------------------------------------
// K2: reduce partials -> J (parallel); rodrigues; lrot table (+pad); chain; M
// ---------------------------------------------------------------------------
__global__ __launch_bounds__(256) void k2_small(
    const float* __restrict__ pose, float* __restrict__ ws)
{
    __shared__ float Jl[NJ * 3];
    __shared__ float Rl[NJ * 9];
    __shared__ float Gl[NJ * 12];
    __shared__ float lrotl[NP];
    __shared__ float cs[3 * 72];
    const int t = threadIdx.x;

    // phase A: parallel partial reduction (3 chunks x 72 outputs)
    if (t < 216) {
        const int q = t % 72, chunk = t / 72;
        const int b0 = chunk * 66;
        const int b1 = min(K1_BLOCKS, b0 + 66);
        float s = 0.f;
        for (int b = b0; b < b1; b++) s += ws[PARTIAL_OFF + b * 72 + q];
        cs[chunk * 72 + q] = s;
    }
    __syncthreads();
    if (t < 72) Jl[t] = cs[t] + cs[72 + t] + cs[144 + t];
    __syncthreads();

    if (t < NJ) {
        const float x = pose[t * 3 + 0], y = pose[t * 3 + 1], z = pose[t * 3 + 2];
        const float ex = x + 1e-8f, ey = y + 1e-8f, ez = z + 1e-8f;
        const float theta = sqrtf(ex * ex + ey * ey + ez * ez);
        const float inv = 1.f / theta;
        const float rx = x * inv, ry = y * inv, rz = z * inv;
        const float c = cosf(theta), s = sinf(theta), omc = 1.f - c;
        float R[9];
        R[0] = c + omc * rx * rx;      R[1] = omc * rx * ry - s * rz; R[2] = omc * rx * rz + s * ry;
        R[3] = omc * ry * rx + s * rz; R[4] = c + omc * ry * ry;      R[5] = omc * ry * rz - s * rx;
        R[6] = omc * rz * rx - s * ry; R[7] = omc * rz * ry + s * rx; R[8] = c + omc * rz * rz;
#pragma unroll
        for (int q = 0; q < 9; q++) Rl[t * 9 + q] = R[q];
        if (t >= 1) {
#pragma unroll
            for (int q = 0; q < 9; q++)
                lrotl[(t - 1) * 9 + q] = R[q] - ((q == 0 || q == 4 || q == 8) ? 1.f : 0.f);
        }
    }
    __syncthreads();

    // lrot table with zero pad at [207]
    if (t < 208) ws[LROT_OFF + t] = (t < NP) ? lrotl[t] : 0.f;

    for (int L = 0; L < 9; L++) {
        if (t < NJ && d_lvl[t] == L) {
            if (t == 0) {
#pragma unroll
                for (int r = 0; r < 3; r++) {
                    Gl[r * 4 + 0] = Rl[r * 3 + 0];
                    Gl[r * 4 + 1] = Rl[r * 3 + 1];
                    Gl[r * 4 + 2] = Rl[r * 3 + 2];
                    Gl[r * 4 + 3] = Jl[r];
                }
            } else {
                const int p = d_par[t];
                const float tx = Jl[t * 3 + 0] - Jl[p * 3 + 0];
                const float ty = Jl[t * 3 + 1] - Jl[p * 3 + 1];
                const float tz = Jl[t * 3 + 2] - Jl[p * 3 + 2];
#pragma unroll
                for (int r = 0; r < 3; r++) {
                    const float g0 = Gl[p * 12 + r * 4 + 0];
                    const float g1 = Gl[p * 12 + r * 4 + 1];
                    const float g2 = Gl[p * 12 + r * 4 + 2];
                    const float g3 = Gl[p * 12 + r * 4 + 3];
                    Gl[t * 12 + r * 4 + 0] = g0 * Rl[t * 9 + 0] + g1 * Rl[t * 9 + 3] + g2 * Rl[t * 9 + 6];
                    Gl[t * 12 + r * 4 + 1] = g0 * Rl[t * 9 + 1] + g1 * Rl[t * 9 + 4] + g2 * Rl[t * 9 + 7];
                    Gl[t * 12 + r * 4 + 2] = g0 * Rl[t * 9 + 2] + g1 * Rl[t * 9 + 5] + g2 * Rl[t * 9 + 8];
                    Gl[t * 12 + r * 4 + 3] = g0 * tx + g1 * ty + g2 * tz + g3;
                }
            }
        }
        __syncthreads();
    }

    if (t < NJ) {
        const float jx = Jl[t * 3 + 0], jy = Jl[t * 3 + 1], jz = Jl[t * 3 + 2];
#pragma unroll
        for (int r = 0; r < 3; r++) {
            const float g0 = Gl[t * 12 + r * 4 + 0];
            const float g1 = Gl[t * 12 + r * 4 + 1];
            const float g2 = Gl[t * 12 + r * 4 + 2];
            const float g3 = Gl[t * 12 + r * 4 + 3];
            ws[M_OFF + t * 12 + r * 4 + 0] = g0;
            ws[M_OFF + t * 12 + r * 4 + 1] = g1;
            ws[M_OFF + t * 12 + r * 4 + 2] = g2;
            ws[M_OFF + t * 12 + r * 4 + 3] = g3 - (g0 * jx + g1 * jy + g2 * jz);
        }
    }
}

// ---------------------------------------------------------------------------
// K3a: LDS-tiled pose GEMV. Block stages 64 rows of posedirs (52992 B) with
// 13 batched float4 loads/thread, then thread (q=wave, row=lane) reduces a
// 52-col quarter from LDS (lrot = same-address broadcast; tile = 2-way
// conflict, free). Quarter partials combined via LDS. out <- vposed.
// ---------------------------------------------------------------------------
__global__ __launch_bounds__(256, 2) void k3a_posegemv(
    const float* __restrict__ betas, const float* __restrict__ shapedirs,
    const float* __restrict__ v_template, const float* __restrict__ posedirs,
    const float* __restrict__ ws, float* __restrict__ out)
{
    __shared__ float4 tile4[3313];   // 64 rows * 207 float4s + 1 zero pad
    __shared__ float sdt[640];
    __shared__ float lrotl[208];
    __shared__ float part[256];
    __shared__ float betl[NBETA];

    const int t = threadIdx.x;
    const int blk = blockIdx.x;
    const int rbase = blk * 64;
    const int rows = min(64, NROWS - rbase);      // 64, or 48 for last block
    const int nf4 = (rows * 207) >> 2;            // 3312 or 2484 (both exact)

    // ---- stage posedirs tile: batched loads, then LDS writes ----
    const float4* gp = (const float4*)posedirs + (size_t)blk * 3312;
    const float4 z4 = {0.f, 0.f, 0.f, 0.f};
    float4 r[13];
#pragma unroll
    for (int i = 0; i < 13; i++) {
        const int idx = i * 256 + t;
        r[i] = (idx < nf4) ? gp[idx] : z4;
    }
#pragma unroll
    for (int i = 0; i < 13; i++) {
        const int idx = i * 256 + t;
        if (idx < nf4) tile4[idx] = r[i];
    }
    // shapedirs tile (rows*10 floats, 16B-aligned)
    if (t < ((rows * 10) >> 2))
        ((float4*)sdt)[t] = ((const float4*)(shapedirs + (size_t)rbase * 10))[t];
    // lrot table (207 + zero pad)
    if (t < 52) ((float4*)lrotl)[t] = ((const float4*)(ws + LROT_OFF))[t];
    if (t < NBETA) betl[t] = betas[t];
    if (t == 0) tile4[3312] = z4;   // pad so q=3's 52nd product is x*0 with defined x
    __syncthreads();

    // ---- compute: quarter-split reduction ----
    const int row = t & 63, q = t >> 6;
    const float* tile = (const float*)tile4;
    const float* rp = tile + row * 207 + q * 52;
    const float* lp = lrotl + q * 52;             // lp[51] for q=3 -> lrotl[207] = 0
    float p = 0.f;
#pragma unroll
    for (int j = 0; j < 52; j++) p += rp[j] * lp[j];
    part[q * 64 + row] = p;
    __syncthreads();

    if (t < 64 && rbase + t < NROWS) {
        float vp = part[t] + part[64 + t] + part[128 + t] + part[192 + t];
#pragma unroll
        for (int c = 0; c < NBETA; c++) vp += sdt[t * 10 + c] * betl[c];
        out[rbase + t] = vp + v_template[rbase + t];
    }
}

// ---------------------------------------------------------------------------
// K3b: skinning, one vertex per thread, in-place on out (vposed -> final v)
// ---------------------------------------------------------------------------
__global__ __launch_bounds__(256) void k3b_skin(
    const float* __restrict__ trans, const float* __restrict__ weights,
    const float* __restrict__ ws, float* __restrict__ out)
{
    __shared__ float Ml[288];
    const int t = threadIdx.x;
    Ml[t] = ws[M_OFF + t];
    if (t < 32) Ml[256 + t] = ws[M_OFF + 256 + t];
    __syncthreads();

    const int v = blockIdx.x * 256 + t;
    if (v >= NV) return;

    const float4* w4 = (const float4*)(weights + (size_t)v * 24);
    float wj[24];
#pragma unroll
    for (int q = 0; q < 6; q++) {
        const float4 w = w4[q];
        wj[q * 4 + 0] = w.x; wj[q * 4 + 1] = w.y;
        wj[q * 4 + 2] = w.z; wj[q * 4 + 3] = w.w;
    }

    float T[12];
#pragma unroll
    for (int q = 0; q < 12; q++) T[q] = 0.f;
#pragma unroll
    for (int j = 0; j < NJ; j++) {
        const float w = wj[j];
#pragma unroll
        for (int q = 0; q < 12; q++) T[q] += w * Ml[j * 12 + q];
    }

    const float p0 = out[(size_t)v * 3 + 0];
    const float p1 = out[(size_t)v * 3 + 1];
    const float p2 = out[(size_t)v * 3 + 2];
    out[(size_t)v * 3 + 0] = T[0] * p0 + T[1] * p1 + T[2]  * p2 + T[3]  + trans[0];
    out[(size_t)v * 3 + 1] = T[4] * p0 + T[5] * p1 + T[6]  * p2 + T[7]  + trans[1];
    out[(size_t)v * 3 + 2] = T[8] * p0 + T[9] * p1 + T[10] * p2 + T[11] + trans[2];
}

extern "C" void kernel_launch(void* const* d_in, const int* in_sizes, int n_in,
                              void* d_out, int out_size, void* d_ws, size_t ws_size,
                              hipStream_t stream) {
    const float* betas      = (const float*)d_in[0];
    const float* pose       = (const float*)d_in[1];
    const float* trans      = (const float*)d_in[2];
    const float* shapedirs  = (const float*)d_in[3];
    const float* v_template = (const float*)d_in[4];
    const float* Jreg       = (const float*)d_in[5];
    const float* weights    = (const float*)d_in[6];
    const float* posedirs   = (const float*)d_in[7];
    float* ws  = (float*)d_ws;
    float* out = (float*)d_out;

    k1_partialJ<<<dim3(K1_BLOCKS), dim3(256), 0, stream>>>(betas, shapedirs, v_template, Jreg, ws);
    k2_small<<<dim3(1), dim3(256), 0, stream>>>(pose, ws);
    k3a_posegemv<<<dim3(K3A_BLOCKS), dim3(256), 0, stream>>>(
        betas, shapedirs, v_template, posedirs, ws, out);
    k3b_skin<<<dim3((NV + 255) / 256), dim3(256), 0, stream>>>(trans, weights, ws, out);
}

// Round 7
// 80.551 us; speedup vs baseline: 1.0281x; 1.0281x over previous
//
#include <hip/hip_runtime.h>

#define NV 50000
#define NJ 24
#define NBETA 10
#define NP 207          // (24-1)*9
#define NROWS 150000    // NV*3
#define ROWGROUPS 37500 // NROWS/4 ; 4 rows = 207 float4s exactly, 16B-aligned

// K1 grid
#define K1_BLOCKS 196   // 196 * 256 = 50176 >= 50000

// K3 fused: 32 vertices / block = 96 rows = 24 groups of 4 rows
#define VPB 32
#define RPB 96
#define GPB 24
#define K3_BLOCKS 1563  // ceil(50000/32)

// ws layout (float offsets)
#define PARTIAL_OFF 0        // 196*72 = 14112 floats
#define LROT4_OFF   14592    // 828 floats: lrotmin repeated 4x (byte off 58368, 16B-aligned)
#define M_OFF       15424    // 24*12 = 288 floats

typedef float f4 __attribute__((ext_vector_type(4)));

__device__ const int d_par[NJ] = {0,0,0,0,1,2,3,4,5,6,7,8,9,9,9,12,13,14,16,17,18,19,20,21};
__device__ const int d_lvl[NJ] = {0,1,1,1,2,2,2,3,3,3,4,4,4,4,4,5,5,5,6,6,7,7,8,8};

// ---------------------------------------------------------------------------
// K1: per-block partial J = J_regressor @ v_shaped  (one 256-vertex tile/block)
// ---------------------------------------------------------------------------
__global__ __launch_bounds__(256) void k1_partialJ(
    const float* __restrict__ betas, const float* __restrict__ shapedirs,
    const float* __restrict__ v_template, const float* __restrict__ Jreg,
    float* __restrict__ ws)
{
    __shared__ float sd[256 * 30];
    __shared__ float vt[256 * 3];
    __shared__ float bet[NBETA];
    __shared__ float red[4 * 72];

    const int t = threadIdx.x;
    const int blk = blockIdx.x;
    if (t < NBETA) bet[t] = betas[t];

    const int vbase = blk * 256;
    const int nv    = min(256, NV - vbase);   // 256, or 80 for last block
    {
        const int nf4 = (nv * 30) >> 2;       // divisible by 4 for nv in {256,80}
        const float4* sdg = (const float4*)(shapedirs + (size_t)vbase * 30);
        for (int i = t; i < nf4; i += 256) ((float4*)sd)[i] = sdg[i];
        const float* vtg = v_template + (size_t)vbase * 3;
        const int nf3 = nv * 3;
        for (int i = t; i < nf3; i += 256) vt[i] = vtg[i];
    }
    __syncthreads();

    float accJ[72];
#pragma unroll
    for (int q = 0; q < 72; q++) accJ[q] = 0.f;

    const int v = vbase + t;
    if (v < NV) {
        float vs0 = vt[t * 3 + 0], vs1 = vt[t * 3 + 1], vs2 = vt[t * 3 + 2];
#pragma unroll
        for (int i = 0; i < NBETA; i++) {
            const float b = bet[i];
            vs0 += sd[t * 30 + 0 * 10 + i] * b;
            vs1 += sd[t * 30 + 1 * 10 + i] * b;
            vs2 += sd[t * 30 + 2 * 10 + i] * b;
        }
#pragma unroll
        for (int j = 0; j < NJ; j++) {
            const float w = Jreg[(size_t)j * NV + v];
            accJ[j * 3 + 0] += w * vs0;
            accJ[j * 3 + 1] += w * vs1;
            accJ[j * 3 + 2] += w * vs2;
        }
    }

    const int lane = t & 63, wv = t >> 6;
#pragma unroll
    for (int q = 0; q < 72; q++) {
        float x = accJ[q];
#pragma unroll
        for (int m = 1; m < 64; m <<= 1) x += __shfl_xor(x, m);
        if (lane == 0) red[wv * 72 + q] = x;
    }
    __syncthreads();
    if (t < 72)
        ws[PARTIAL_OFF + blk * 72 + t] = red[t] + red[72 + t] + red[144 + t] + red[216 + t];
}

// ---------------------------------------------------------------------------
// K2: reduce partials -> J; rodrigues; expanded lrotmin table; chain; M
// ---------------------------------------------------------------------------
__global__ __launch_bounds__(256) void k2_small(
    const float* __restrict__ pose, float* __restrict__ ws)
{
    __shared__ float Jl[NJ * 3];
    __shared__ float Rl[NJ * 9];
    __shared__ float Gl[NJ * 12];
    __shared__ float lrotl[NP];
    const int t = threadIdx.x;

    if (t < 72) {
        float s0 = 0.f, s1 = 0.f;
        for (int b = 0; b < K1_BLOCKS; b += 2) {
            s0 += ws[PARTIAL_OFF + b * 72 + t];
            s1 += ws[PARTIAL_OFF + (b + 1) * 72 + t];
        }
        Jl[t] = s0 + s1;
    }
    __syncthreads();

    if (t < NJ) {
        const float x = pose[t * 3 + 0], y = pose[t * 3 + 1], z = pose[t * 3 + 2];
        const float ex = x + 1e-8f, ey = y + 1e-8f, ez = z + 1e-8f;
        const float theta = sqrtf(ex * ex + ey * ey + ez * ez);
        const float inv = 1.f / theta;
        const float rx = x * inv, ry = y * inv, rz = z * inv;
        const float c = cosf(theta), s = sinf(theta), omc = 1.f - c;
        float R[9];
        R[0] = c + omc * rx * rx;      R[1] = omc * rx * ry - s * rz; R[2] = omc * rx * rz + s * ry;
        R[3] = omc * ry * rx + s * rz; R[4] = c + omc * ry * ry;      R[5] = omc * ry * rz - s * rx;
        R[6] = omc * rz * rx - s * ry; R[7] = omc * rz * ry + s * rx; R[8] = c + omc * rz * rz;
#pragma unroll
        for (int q = 0; q < 9; q++) Rl[t * 9 + q] = R[q];
        if (t >= 1) {
#pragma unroll
            for (int q = 0; q < 9; q++)
                lrotl[(t - 1) * 9 + q] = R[q] - ((q == 0 || q == 4 || q == 8) ? 1.f : 0.f);
        }
    }
    __syncthreads();

    // expanded lrotmin: ws[LROT4_OFF + i] = lrotl[i % 207], i in [0, 828)
    for (int i = t; i < 4 * NP; i += 256) {
        int c = i;
        if (c >= 3 * NP) c -= 3 * NP;
        else if (c >= 2 * NP) c -= 2 * NP;
        else if (c >= NP) c -= NP;
        ws[LROT4_OFF + i] = lrotl[c];
    }

    for (int L = 0; L < 9; L++) {
        if (t < NJ && d_lvl[t] == L) {
            if (t == 0) {
#pragma unroll
                for (int r = 0; r < 3; r++) {
                    Gl[r * 4 + 0] = Rl[r * 3 + 0];
                    Gl[r * 4 + 1] = Rl[r * 3 + 1];
                    Gl[r * 4 + 2] = Rl[r * 3 + 2];
                    Gl[r * 4 + 3] = Jl[r];
                }
            } else {
                const int p = d_par[t];
                const float tx = Jl[t * 3 + 0] - Jl[p * 3 + 0];
                const float ty = Jl[t * 3 + 1] - Jl[p * 3 + 1];
                const float tz = Jl[t * 3 + 2] - Jl[p * 3 + 2];
#pragma unroll
                for (int r = 0; r < 3; r++) {
                    const float g0 = Gl[p * 12 + r * 4 + 0];
                    const float g1 = Gl[p * 12 + r * 4 + 1];
                    const float g2 = Gl[p * 12 + r * 4 + 2];
                    const float g3 = Gl[p * 12 + r * 4 + 3];
                    Gl[t * 12 + r * 4 + 0] = g0 * Rl[t * 9 + 0] + g1 * Rl[t * 9 + 3] + g2 * Rl[t * 9 + 6];
                    Gl[t * 12 + r * 4 + 1] = g0 * Rl[t * 9 + 1] + g1 * Rl[t * 9 + 4] + g2 * Rl[t * 9 + 7];
                    Gl[t * 12 + r * 4 + 2] = g0 * Rl[t * 9 + 2] + g1 * Rl[t * 9 + 5] + g2 * Rl[t * 9 + 8];
                    Gl[t * 12 + r * 4 + 3] = g0 * tx + g1 * ty + g2 * tz + g3;
                }
            }
        }
        __syncthreads();
    }

    if (t < NJ) {
        const float jx = Jl[t * 3 + 0], jy = Jl[t * 3 + 1], jz = Jl[t * 3 + 2];
#pragma unroll
        for (int r = 0; r < 3; r++) {
            const float g0 = Gl[t * 12 + r * 4 + 0];
            const float g1 = Gl[t * 12 + r * 4 + 1];
            const float g2 = Gl[t * 12 + r * 4 + 2];
            const float g3 = Gl[t * 12 + r * 4 + 3];
            ws[M_OFF + t * 12 + r * 4 + 0] = g0;
            ws[M_OFF + t * 12 + r * 4 + 1] = g1;
            ws[M_OFF + t * 12 + r * 4 + 2] = g2;
            ws[M_OFF + t * 12 + r * 4 + 3] = g3 - (g0 * jx + g1 * jy + g2 * jz);
        }
    }
}

// ---------------------------------------------------------------------------
// K3 fused: identical to R3 EXCEPT posedirs/shapedirs reads are non-temporal
// (via clang native vector type f4 — __builtin_nontemporal_load rejects the
// HIP_vector_type struct). Single-variable A/B vs the 55.7us R3 run.
// ---------------------------------------------------------------------------
__global__ __launch_bounds__(256) void k3_fused(
    const float* __restrict__ betas, const float* __restrict__ trans,
    const float* __restrict__ shapedirs, const float* __restrict__ v_template,
    const float* __restrict__ weights, const float* __restrict__ posedirs,
    const float* __restrict__ ws, float* __restrict__ out)
{
    __shared__ float vposed[RPB];
    __shared__ float Ml[288];

    const int t = threadIdx.x;
    const int lane = t & 63, wv = t >> 6;
    const int blk = blockIdx.x;

    Ml[t] = ws[M_OFF + t];
    if (t < 32) Ml[256 + t] = ws[M_OFF + 256 + t];

    const f4 z4 = {0.f, 0.f, 0.f, 0.f};

    // per-lane coefficient fragments: coeff for slot (k,e) = lrotmin[(4*(lane+64k)+e)%207]
    const f4* E4 = (const f4*)(ws + LROT4_OFF);
    const f4 e40 = E4[lane];
    const f4 e41 = E4[64 + lane];
    const f4 e42 = E4[128 + lane];
    const f4 e43 = (lane < 15) ? E4[192 + lane] : z4;

    // per-lane beta for the shapedirs slice (lanes 0..39: flat = lane, col = lane%10)
    const int bcol = (lane < 10) ? lane : (lane < 20) ? lane - 10 : (lane < 30) ? lane - 20 : lane - 30;
    const float bscal = (lane < 40) ? betas[bcol] : 0.f;

    // group accumulation: 4 row-accumulators, compile-time lane thresholds
    auto accum = [&](const f4& q0, const f4& q1, const f4& q2, const f4& q3,
                     float sv, float& a0, float& a1, float& a2, float& a3) {
        // k=0: flat = 4*lane+e, boundary 207
        {
            const float v0 = q0.x * e40.x, v1 = q0.y * e40.y, v2 = q0.z * e40.z, v3 = q0.w * e40.w;
            const float s = v0 + v1 + v2;
            if (lane < 52) a0 += s; else a1 += s;
            if (lane < 51) a0 += v3; else a1 += v3;
        }
        // k=1: flat = 256+4*lane+e, boundary 414
        {
            const float v0 = q1.x * e41.x, v1 = q1.y * e41.y, v2 = q1.z * e41.z, v3 = q1.w * e41.w;
            const float s01 = v0 + v1, s23 = v2 + v3;
            if (lane < 40) a1 += s01; else a2 += s01;
            if (lane < 39) a1 += s23; else a2 += s23;
        }
        // k=2: flat = 512+4*lane+e, boundary 621
        {
            const float v0 = q2.x * e42.x, v1 = q2.y * e42.y, v2 = q2.z * e42.z, v3 = q2.w * e42.w;
            const float s123 = v1 + v2 + v3;
            if (lane < 28) a2 += v0; else a3 += v0;
            if (lane < 27) a2 += s123; else a3 += s123;
        }
        // k=3 tail: lanes 0..14, all row 3
        if (lane < 15) a3 += q3.x * e43.x + q3.y * e43.y + q3.z * e43.z + q3.w * e43.w;
        // shapedirs: lanes 0..39, row = lane/10
        {
            const float v = sv * bscal;
            if (lane < 10) a0 += v;
            else if (lane < 20) a1 += v;
            else if (lane < 30) a2 += v;
            else if (lane < 40) a3 += v;
        }
    };

    const int gbase = blk * GPB + wv * 6;
#pragma unroll
    for (int i = 0; i < 6; i += 2) {
        const int gA = gbase + i, gB = gA + 1;
        const bool okA = gA < ROWGROUPS, okB = gB < ROWGROUPS;

        f4 pa0, pa1, pa2, pa3, pb0, pb1, pb2, pb3;
        float sa = 0.f, sb = 0.f;
        if (okA) {
            const f4* G = (const f4*)posedirs + (size_t)gA * 207;
            pa0 = __builtin_nontemporal_load(G + lane);
            pa1 = __builtin_nontemporal_load(G + 64 + lane);
            pa2 = __builtin_nontemporal_load(G + 128 + lane);
            pa3 = (lane < 15) ? __builtin_nontemporal_load(G + 192 + lane) : z4;
            sa  = (lane < 40) ? __builtin_nontemporal_load(shapedirs + (size_t)gA * 40 + lane) : 0.f;
        } else { pa0 = pa1 = pa2 = pa3 = z4; }
        if (okB) {
            const f4* G = (const f4*)posedirs + (size_t)gB * 207;
            pb0 = __builtin_nontemporal_load(G + lane);
            pb1 = __builtin_nontemporal_load(G + 64 + lane);
            pb2 = __builtin_nontemporal_load(G + 128 + lane);
            pb3 = (lane < 15) ? __builtin_nontemporal_load(G + 192 + lane) : z4;
            sb  = (lane < 40) ? __builtin_nontemporal_load(shapedirs + (size_t)gB * 40 + lane) : 0.f;
        } else { pb0 = pb1 = pb2 = pb3 = z4; }

        float a0 = 0.f, a1 = 0.f, a2 = 0.f, a3 = 0.f;
        float b0 = 0.f, b1 = 0.f, b2 = 0.f, b3 = 0.f;
        accum(pa0, pa1, pa2, pa3, sa, a0, a1, a2, a3);
        accum(pb0, pb1, pb2, pb3, sb, b0, b1, b2, b3);

#pragma unroll
        for (int m = 1; m < 64; m <<= 1) {
            a0 += __shfl_xor(a0, m); a1 += __shfl_xor(a1, m);
            a2 += __shfl_xor(a2, m); a3 += __shfl_xor(a3, m);
            b0 += __shfl_xor(b0, m); b1 += __shfl_xor(b1, m);
            b2 += __shfl_xor(b2, m); b3 += __shfl_xor(b3, m);
        }
        if (lane == 0) {
            if (okA) {
                const int gl = gA - blk * GPB;
                vposed[gl * 4 + 0] = a0; vposed[gl * 4 + 1] = a1;
                vposed[gl * 4 + 2] = a2; vposed[gl * 4 + 3] = a3;
            }
            if (okB) {
                const int gl = gB - blk * GPB;
                vposed[gl * 4 + 0] = b0; vposed[gl * 4 + 1] = b1;
                vposed[gl * 4 + 2] = b2; vposed[gl * 4 + 3] = b3;
            }
        }
    }
    __syncthreads();

    // ---- phase 2: skinning, threads 0..31, one vertex each ----
    if (t < VPB) {
        const int v = blk * VPB + t;
        if (v < NV) {
            const float4* w4 = (const float4*)(weights + (size_t)v * 24);
            float wj[24];
#pragma unroll
            for (int q = 0; q < 6; q++) {
                const float4 w = w4[q];
                wj[q * 4 + 0] = w.x; wj[q * 4 + 1] = w.y;
                wj[q * 4 + 2] = w.z; wj[q * 4 + 3] = w.w;
            }
            float T[12];
#pragma unroll
            for (int q = 0; q < 12; q++) T[q] = 0.f;
#pragma unroll
            for (int j = 0; j < NJ; j++) {
                const float w = wj[j];
#pragma unroll
                for (int q = 0; q < 12; q++) T[q] += w * Ml[j * 12 + q];
            }
            const float p0 = vposed[t * 3 + 0] + v_template[(size_t)v * 3 + 0];
            const float p1 = vposed[t * 3 + 1] + v_template[(size_t)v * 3 + 1];
            const float p2 = vposed[t * 3 + 2] + v_template[(size_t)v * 3 + 2];
            out[(size_t)v * 3 + 0] = T[0] * p0 + T[1] * p1 + T[2]  * p2 + T[3]  + trans[0];
            out[(size_t)v * 3 + 1] = T[4] * p0 + T[5] * p1 + T[6]  * p2 + T[7]  + trans[1];
            out[(size_t)v * 3 + 2] = T[8] * p0 + T[9] * p1 + T[10] * p2 + T[11] + trans[2];
        }
    }
}

extern "C" void kernel_launch(void* const* d_in, const int* in_sizes, int n_in,
                              void* d_out, int out_size, void* d_ws, size_t ws_size,
                              hipStream_t stream) {
    const float* betas      = (const float*)d_in[0];
    const float* pose       = (const float*)d_in[1];
    const float* trans      = (const float*)d_in[2];
    const float* shapedirs  = (const float*)d_in[3];
    const float* v_template = (const float*)d_in[4];
    const float* Jreg       = (const float*)d_in[5];
    const float* weights    = (const float*)d_in[6];
    const float* posedirs   = (const float*)d_in[7];
    float* ws  = (float*)d_ws;
    float* out = (float*)d_out;

    k1_partialJ<<<dim3(K1_BLOCKS), dim3(256), 0, stream>>>(betas, shapedirs, v_template, Jreg, ws);
    k2_small<<<dim3(1), dim3(256), 0, stream>>>(pose, ws);
    k3_fused<<<dim3(K3_BLOCKS), dim3(256), 0, stream>>>(
        betas, trans, shapedirs, v_template, weights, posedirs, ws, out);
}

// Round 8
// 54.893 us; speedup vs baseline: 1.5086x; 1.4674x over previous
//
#include <hip/hip_runtime.h>

#define NV 50000
#define NJ 24
#define NBETA 10
#define NP 207          // (24-1)*9
#define NROWS 150000    // NV*3
#define ROWGROUPS 37500 // NROWS/4

// K1 grid
#define K1_BLOCKS 196   // 196 * 256 = 50176 >= 50000

// K3 fused: 32 vertices / block = 96 rows = 24 groups of 4 rows
#define VPB 32
#define RPB 96
#define GPB 24
#define K3_BLOCKS 1563  // ceil(50000/32)

// ws layout (float offsets)
#define PARTIAL_OFF 0        // 196*72 = 14112 floats
#define LROT_OFF    14336    // 207 floats
#define M_OFF       14592    // 24*12 = 288 floats

__device__ const int d_par[NJ] = {0,0,0,0,1,2,3,4,5,6,7,8,9,9,9,12,13,14,16,17,18,19,20,21};
__device__ const int d_lvl[NJ] = {0,1,1,1,2,2,2,3,3,3,4,4,4,4,4,5,5,5,6,6,7,7,8,8};

// ---------------------------------------------------------------------------
// K1: per-block partial J = J_regressor @ v_shaped  (one 256-vertex tile/block)
// ---------------------------------------------------------------------------
__global__ __launch_bounds__(256) void k1_partialJ(
    const float* __restrict__ betas, const float* __restrict__ shapedirs,
    const float* __restrict__ v_template, const float* __restrict__ Jreg,
    float* __restrict__ ws)
{
    __shared__ float sd[256 * 30];
    __shared__ float vt[256 * 3];
    __shared__ float bet[NBETA];
    __shared__ float red[4 * 72];

    const int t = threadIdx.x;
    const int blk = blockIdx.x;
    if (t < NBETA) bet[t] = betas[t];

    const int vbase = blk * 256;
    const int nv    = min(256, NV - vbase);   // 256, or 80 for last block
    {
        const int nf4 = (nv * 30) >> 2;       // divisible by 4 for nv in {256,80}
        const float4* sdg = (const float4*)(shapedirs + (size_t)vbase * 30);
        for (int i = t; i < nf4; i += 256) ((float4*)sd)[i] = sdg[i];
        const float* vtg = v_template + (size_t)vbase * 3;
        const int nf3 = nv * 3;
        for (int i = t; i < nf3; i += 256) vt[i] = vtg[i];
    }
    __syncthreads();

    float accJ[72];
#pragma unroll
    for (int q = 0; q < 72; q++) accJ[q] = 0.f;

    const int v = vbase + t;
    if (v < NV) {
        float vs0 = vt[t * 3 + 0], vs1 = vt[t * 3 + 1], vs2 = vt[t * 3 + 2];
#pragma unroll
        for (int i = 0; i < NBETA; i++) {
            const float b = bet[i];
            vs0 += sd[t * 30 + 0 * 10 + i] * b;
            vs1 += sd[t * 30 + 1 * 10 + i] * b;
            vs2 += sd[t * 30 + 2 * 10 + i] * b;
        }
#pragma unroll
        for (int j = 0; j < NJ; j++) {
            const float w = Jreg[(size_t)j * NV + v];
            accJ[j * 3 + 0] += w * vs0;
            accJ[j * 3 + 1] += w * vs1;
            accJ[j * 3 + 2] += w * vs2;
        }
    }

    const int lane = t & 63, wv = t >> 6;
#pragma unroll
    for (int q = 0; q < 72; q++) {
        float x = accJ[q];
#pragma unroll
        for (int m = 1; m < 64; m <<= 1) x += __shfl_xor(x, m);
        if (lane == 0) red[wv * 72 + q] = x;
    }
    __syncthreads();
    if (t < 72)
        ws[PARTIAL_OFF + blk * 72 + t] = red[t] + red[72 + t] + red[144 + t] + red[216 + t];
}

// ---------------------------------------------------------------------------
// K2: reduce partials -> J; rodrigues; kinematic chain; write lrotmin + M
// ---------------------------------------------------------------------------
__global__ __launch_bounds__(256) void k2_small(
    const float* __restrict__ pose, float* __restrict__ ws)
{
    __shared__ float Jl[NJ * 3];
    __shared__ float Rl[NJ * 9];
    __shared__ float Gl[NJ * 12];
    const int t = threadIdx.x;

    if (t < 72) {
        float s0 = 0.f, s1 = 0.f;
        for (int b = 0; b < K1_BLOCKS; b += 2) {
            s0 += ws[PARTIAL_OFF + b * 72 + t];
            s1 += ws[PARTIAL_OFF + (b + 1) * 72 + t];
        }
        Jl[t] = s0 + s1;
    }
    __syncthreads();

    if (t < NJ) {
        const float x = pose[t * 3 + 0], y = pose[t * 3 + 1], z = pose[t * 3 + 2];
        const float ex = x + 1e-8f, ey = y + 1e-8f, ez = z + 1e-8f;
        const float theta = sqrtf(ex * ex + ey * ey + ez * ez);
        const float inv = 1.f / theta;
        const float rx = x * inv, ry = y * inv, rz = z * inv;
        const float c = cosf(theta), s = sinf(theta), omc = 1.f - c;
        float R[9];
        R[0] = c + omc * rx * rx;      R[1] = omc * rx * ry - s * rz; R[2] = omc * rx * rz + s * ry;
        R[3] = omc * ry * rx + s * rz; R[4] = c + omc * ry * ry;      R[5] = omc * ry * rz - s * rx;
        R[6] = omc * rz * rx - s * ry; R[7] = omc * rz * ry + s * rx; R[8] = c + omc * rz * rz;
#pragma unroll
        for (int q = 0; q < 9; q++) Rl[t * 9 + q] = R[q];
        if (t >= 1) {
#pragma unroll
            for (int q = 0; q < 9; q++)
                ws[LROT_OFF + (t - 1) * 9 + q] = R[q] - ((q == 0 || q == 4 || q == 8) ? 1.f : 0.f);
        }
    }
    __syncthreads();

    for (int L = 0; L < 9; L++) {
        if (t < NJ && d_lvl[t] == L) {
            if (t == 0) {
#pragma unroll
                for (int r = 0; r < 3; r++) {
                    Gl[r * 4 + 0] = Rl[r * 3 + 0];
                    Gl[r * 4 + 1] = Rl[r * 3 + 1];
                    Gl[r * 4 + 2] = Rl[r * 3 + 2];
                    Gl[r * 4 + 3] = Jl[r];
                }
            } else {
                const int p = d_par[t];
                const float tx = Jl[t * 3 + 0] - Jl[p * 3 + 0];
                const float ty = Jl[t * 3 + 1] - Jl[p * 3 + 1];
                const float tz = Jl[t * 3 + 2] - Jl[p * 3 + 2];
#pragma unroll
                for (int r = 0; r < 3; r++) {
                    const float g0 = Gl[p * 12 + r * 4 + 0];
                    const float g1 = Gl[p * 12 + r * 4 + 1];
                    const float g2 = Gl[p * 12 + r * 4 + 2];
                    const float g3 = Gl[p * 12 + r * 4 + 3];
                    Gl[t * 12 + r * 4 + 0] = g0 * Rl[t * 9 + 0] + g1 * Rl[t * 9 + 3] + g2 * Rl[t * 9 + 6];
                    Gl[t * 12 + r * 4 + 1] = g0 * Rl[t * 9 + 1] + g1 * Rl[t * 9 + 4] + g2 * Rl[t * 9 + 7];
                    Gl[t * 12 + r * 4 + 2] = g0 * Rl[t * 9 + 2] + g1 * Rl[t * 9 + 5] + g2 * Rl[t * 9 + 8];
                    Gl[t * 12 + r * 4 + 3] = g0 * tx + g1 * ty + g2 * tz + g3;
                }
            }
        }
        __syncthreads();
    }

    if (t < NJ) {
        const float jx = Jl[t * 3 + 0], jy = Jl[t * 3 + 1], jz = Jl[t * 3 + 2];
#pragma unroll
        for (int r = 0; r < 3; r++) {
            const float g0 = Gl[t * 12 + r * 4 + 0];
            const float g1 = Gl[t * 12 + r * 4 + 1];
            const float g2 = Gl[t * 12 + r * 4 + 2];
            const float g3 = Gl[t * 12 + r * 4 + 3];
            ws[M_OFF + t * 12 + r * 4 + 0] = g0;
            ws[M_OFF + t * 12 + r * 4 + 1] = g1;
            ws[M_OFF + t * 12 + r * 4 + 2] = g2;
            ws[M_OFF + t * 12 + r * 4 + 3] = g3 - (g0 * jx + g1 * jy + g2 * jz);
        }
    }
}

// ---------------------------------------------------------------------------
// K3 fused: R3 structure (16 lanes/row, 4 rows/group, scalar-dword loads),
// MLP deepened 3x: all 6 groups' 84 loads issued straight-line before any
// FMA/butterfly (hot path branch-free; guarded path only for the last block).
// Then skinning (threads 0..31).
// ---------------------------------------------------------------------------
__global__ __launch_bounds__(256) void k3_fused(
    const float* __restrict__ betas, const float* __restrict__ trans,
    const float* __restrict__ shapedirs, const float* __restrict__ v_template,
    const float* __restrict__ weights, const float* __restrict__ posedirs,
    const float* __restrict__ ws, float* __restrict__ out)
{
    __shared__ float vposed[RPB];
    __shared__ float Ml[288];

    const int t = threadIdx.x;
    const int lane = t & 63, wv = t >> 6;
    const int l16 = lane & 15, g = lane >> 4;
    const int blk = blockIdx.x;

    Ml[t] = ws[M_OFF + t];
    if (t < 32) Ml[256 + t] = ws[M_OFF + 256 + t];

    // lrotmin fragments: lane owns cols {l16, 16+l16, ..., 176+l16} + tail
    float lrk[12];
#pragma unroll
    for (int k = 0; k < 12; k++) lrk[k] = ws[LROT_OFF + k * 16 + l16];
    const float lr12 = (l16 < 15) ? ws[LROT_OFF + 192 + l16] : 0.f;
    const float bet  = (l16 < NBETA) ? betas[l16] : 0.f;

    // ---- phase 1: 6 groups straight-line ----
    const int gbase = blk * GPB + wv * 6;
    float pv[6][12];
    float tv[6], sv[6];

    if (gbase + 5 < ROWGROUPS) {
        // hot path: no bounds checks, all 84 loads issued back-to-back
#pragma unroll
        for (int i = 0; i < 6; i++) {
            const int row = (gbase + i) * 4 + g;
            const float* pd = posedirs + (size_t)row * NP;
#pragma unroll
            for (int k = 0; k < 12; k++) pv[i][k] = pd[k * 16 + l16];
            tv[i] = (l16 < 15) ? pd[192 + l16] : 0.f;
            sv[i] = (l16 < NBETA) ? shapedirs[(size_t)row * NBETA + l16] : 0.f;
        }
    } else {
#pragma unroll
        for (int i = 0; i < 6; i++) {
            const bool ok = (gbase + i) < ROWGROUPS;
            const int row = ok ? ((gbase + i) * 4 + g) : 0;
            const float* pd = posedirs + (size_t)row * NP;
#pragma unroll
            for (int k = 0; k < 12; k++) pv[i][k] = ok ? pd[k * 16 + l16] : 0.f;
            tv[i] = (ok && l16 < 15) ? pd[192 + l16] : 0.f;
            sv[i] = (ok && l16 < NBETA) ? shapedirs[(size_t)row * NBETA + l16] : 0.f;
        }
    }

    float acc[6];
#pragma unroll
    for (int i = 0; i < 6; i++) {
        float a = tv[i] * lr12 + sv[i] * bet;
#pragma unroll
        for (int k = 0; k < 12; k++) a += pv[i][k] * lrk[k];
        acc[i] = a;
    }
#pragma unroll
    for (int m = 1; m < 16; m <<= 1) {
#pragma unroll
        for (int i = 0; i < 6; i++) acc[i] += __shfl_xor(acc[i], m);
    }
    if (l16 == 0) {
#pragma unroll
        for (int i = 0; i < 6; i++) {
            if (gbase + i < ROWGROUPS)
                vposed[(wv * 6 + i) * 4 + g] = acc[i];
        }
    }
    __syncthreads();

    // ---- phase 2: skinning, threads 0..31, one vertex each ----
    if (t < VPB) {
        const int v = blk * VPB + t;
        if (v < NV) {
            const float4* w4 = (const float4*)(weights + (size_t)v * 24);
            float wj[24];
#pragma unroll
            for (int q = 0; q < 6; q++) {
                const float4 w = w4[q];
                wj[q * 4 + 0] = w.x; wj[q * 4 + 1] = w.y;
                wj[q * 4 + 2] = w.z; wj[q * 4 + 3] = w.w;
            }
            float T[12];
#pragma unroll
            for (int q = 0; q < 12; q++) T[q] = 0.f;
#pragma unroll
            for (int j = 0; j < NJ; j++) {
                const float w = wj[j];
#pragma unroll
                for (int q = 0; q < 12; q++) T[q] += w * Ml[j * 12 + q];
            }
            const float p0 = vposed[t * 3 + 0] + v_template[(size_t)v * 3 + 0];
            const float p1 = vposed[t * 3 + 1] + v_template[(size_t)v * 3 + 1];
            const float p2 = vposed[t * 3 + 2] + v_template[(size_t)v * 3 + 2];
            out[(size_t)v * 3 + 0] = T[0] * p0 + T[1] * p1 + T[2]  * p2 + T[3]  + trans[0];
            out[(size_t)v * 3 + 1] = T[4] * p0 + T[5] * p1 + T[6]  * p2 + T[7]  + trans[1];
            out[(size_t)v * 3 + 2] = T[8] * p0 + T[9] * p1 + T[10] * p2 + T[11] + trans[2];
        }
    }
}

extern "C" void kernel_launch(void* const* d_in, const int* in_sizes, int n_in,
                              void* d_out, int out_size, void* d_ws, size_t ws_size,
                              hipStream_t stream) {
    const float* betas      = (const float*)d_in[0];
    const float* pose       = (const float*)d_in[1];
    const float* trans      = (const float*)d_in[2];
    const float* shapedirs  = (const float*)d_in[3];
    const float* v_template = (const float*)d_in[4];
    const float* Jreg       = (const float*)d_in[5];
    const float* weights    = (const float*)d_in[6];
    const float* posedirs   = (const float*)d_in[7];
    float* ws  = (float*)d_ws;
    float* out = (float*)d_out;

    k1_partialJ<<<dim3(K1_BLOCKS), dim3(256), 0, stream>>>(betas, shapedirs, v_template, Jreg, ws);
    k2_small<<<dim3(1), dim3(256), 0, stream>>>(pose, ws);
    k3_fused<<<dim3(K3_BLOCKS), dim3(256), 0, stream>>>(
        betas, trans, shapedirs, v_template, weights, posedirs, ws, out);
}